// Round 21
// baseline (253.273 us; speedup 1.0000x reference)
//
#include <hip/hip_runtime.h>
#include <hip/hip_bf16.h>

#define BATCH 8
#define CHN   192      // d_model
#define LEN   4096     // H*W tokens
#define DI    384      // d_inner
#define NHEAD 6
#define DST   64       // d_state
#define NCHK  16       // chunks (LEN/256)

typedef __attribute__((ext_vector_type(8))) short short8;
typedef __attribute__((ext_vector_type(4))) short short4v;
typedef __attribute__((ext_vector_type(4))) float f32x4;

__device__ __forceinline__ short f2b(float f) {
  unsigned u = __builtin_bit_cast(unsigned, f);
  unsigned r = (u + 0x7FFFu + ((u >> 16) & 1u)) >> 16;  // round-to-nearest-even
  return (short)r;
}
__device__ __forceinline__ float bf2f(short s) {
  unsigned u = ((unsigned)(unsigned short)s) << 16;
  return __builtin_bit_cast(float, u);
}

// ---------------- K1: transposing LayerNorm1: x (g,192,L) f32 -> h1b (g,L,192) bf16
__global__ __launch_bounds__(256) void k_ln1(const float* __restrict__ x,
    const float* __restrict__ w, const float* __restrict__ b, short* __restrict__ h1b) {
  __shared__ float s[192][33];
  __shared__ float red[2][32][8];
  __shared__ float mu_s[32], rs_s[32];
  int bb = blockIdx.y;
  int t0 = blockIdx.x * 32;
  int tid = threadIdx.x;
  for (int i = 0; i < 24; ++i) {
    int idx = tid + i * 256;            // 192*32 = 6144
    int c = idx >> 5, tt = idx & 31;
    s[c][tt] = x[((size_t)bb * CHN + c) * LEN + t0 + tt];
  }
  __syncthreads();
  int tok = tid & 31, part = tid >> 5;
  float sum = 0.f, sq = 0.f;
  for (int c = part * 24; c < part * 24 + 24; ++c) { float v = s[c][tok]; sum += v; sq += v * v; }
  red[0][tok][part] = sum; red[1][tok][part] = sq;
  __syncthreads();
  if (tid < 32) {
    float su = 0.f, qq = 0.f;
    for (int p = 0; p < 8; ++p) { su += red[0][tid][p]; qq += red[1][tid][p]; }
    float mu = su / 192.f;
    float var = qq / 192.f - mu * mu;
    mu_s[tid] = mu; rs_s[tid] = rsqrtf(var + 1e-5f);
  }
  __syncthreads();
  for (int i = 0; i < 24; ++i) {
    int idx = tid + i * 256;
    int c = idx % 192, tt = idx / 192;
    float v = (s[c][tt] - mu_s[tt]) * rs_s[tt] * w[c] + b[c];
    h1b[((size_t)bb * LEN + t0 + tt) * CHN + c] = f2b(v);
  }
}

// ---------------- K2: fused u-view consumer (bf16 h1): Ubf ([l][c]) + dt (f32 acc).
__global__ __launch_bounds__(256) void k_udt(const short* __restrict__ h1b,
    const float* __restrict__ win, const float* __restrict__ dt_bias,
    short* __restrict__ Ub, float* __restrict__ dtb) {
  __shared__ short Utb[192][72];
  __shared__ float Wd[6][192];
  int l0 = blockIdx.x * 64, bb = blockIdx.y;
  int tid = threadIdx.x;
  for (int i = tid; i < 6 * 192; i += 256)
    Wd[i / 192][i % 192] = win[(size_t)(896 + i / 192) * 192 + (i % 192)];
  const short* src = h1b + (size_t)bb * (CHN * LEN);
  for (int i = tid; i < 192 * 8; i += 256) {
    int c = i >> 3, q = i & 7;
    short8 v = *(const short8*)&src[(size_t)c * LEN + l0 + q * 8];
    *(short8*)&Utb[c][q * 8] = v;
  }
  __syncthreads();
  {
    int l = tid >> 2, part = tid & 3;
    short* dst = Ub + ((size_t)bb * LEN + l0 + l) * CHN + part * 48;
#pragma unroll
    for (int q = 0; q < 6; ++q) {
      short8 pk;
#pragma unroll
      for (int j = 0; j < 8; ++j) pk[j] = Utb[part * 48 + q * 8 + j][l];
      *(short8*)&dst[q * 8] = pk;
    }
  }
  int tok = tid & 63, grp = tid >> 6;
  for (int hh = grp; hh < 6; hh += 4) {
    float acc = dt_bias[hh];
    for (int c = 0; c < 192; ++c) acc += bf2f(Utb[c][tok]) * Wd[hh][c];
    dtb[((size_t)bb * LEN + l0 + tok) * NHEAD + hh] =
        (acc > 20.f) ? acc : log1pf(expf(acc));
  }
}

// ---------------- MFMA GEMM: C = A @ W^T, f32 weights. A f32 or bf16 (ABF16).
// EPI 0: C=v ; 1: C=gelu(v+bias) ; 2: C=v+bias ;
// EPI 3: v+bias+resid(row-major; bf16 if RESB) -> TRANSPOSED f32 outT ;
// EPI 4: v + xT(transposed f32 read) -> row-major C (bf16 if OBF16)
template <int EPI, int ABF16, int OBF16, int RESB>
__global__ __launch_bounds__(256) void gemm_mfma(const void* __restrict__ Av,
    const float* __restrict__ W, const float* __restrict__ bias,
    void* __restrict__ Cv, int M, int N, int K, int ldc,
    const void* __restrict__ residv, float* __restrict__ outT) {
  __shared__ short Al[128 * 64];  // row stride 128 B
  __shared__ short Wl[64 * 64];
  int m0 = blockIdx.y * 128, n0 = blockIdx.x * 64;
  int tid = threadIdx.x;
  int lane = tid & 63, wv = tid >> 6;
  int wm = (wv >> 1) * 64, wn = (wv & 1) * 32;
  int l15 = lane & 15, l4 = lane >> 4;
  f32x4 acc[4][2] = {};

  int ra = tid >> 1, ca = (tid & 1) * 32;
  int rw = tid >> 2, cw = (tid & 3) * 16;
  char* ArowL = (char*)Al + ra * 128;
  char* WrowL = (char*)Wl + rw * 128;
  int rxa = (ra & 7) << 4, rxw = (rw & 7) << 4;

  for (int k0 = 0; k0 < K; k0 += 64) {
    if (ABF16) {
      const short* Ag = (const short*)Av + (size_t)(m0 + ra) * K + k0 + ca;
#pragma unroll
      for (int q = 0; q < 4; ++q) {
        short8 pk = *(const short8*)(Ag + q * 8);
        *(short8*)(ArowL + (((ca + q * 8) * 2) ^ rxa)) = pk;
      }
    } else {
      const float* Ag = (const float*)Av + (size_t)(m0 + ra) * K + k0 + ca;
#pragma unroll
      for (int q = 0; q < 4; ++q) {
        float4 v0 = *(const float4*)(Ag + q * 8);
        float4 v1 = *(const float4*)(Ag + q * 8 + 4);
        short8 pk;
        pk[0] = f2b(v0.x); pk[1] = f2b(v0.y); pk[2] = f2b(v0.z); pk[3] = f2b(v0.w);
        pk[4] = f2b(v1.x); pk[5] = f2b(v1.y); pk[6] = f2b(v1.z); pk[7] = f2b(v1.w);
        *(short8*)(ArowL + (((ca + q * 8) * 2) ^ rxa)) = pk;
      }
    }
    {
      const float* Wg = W + (size_t)(n0 + rw) * K + k0 + cw;
#pragma unroll
      for (int q = 0; q < 2; ++q) {
        float4 v0 = *(const float4*)(Wg + q * 8);
        float4 v1 = *(const float4*)(Wg + q * 8 + 4);
        short8 pk;
        pk[0] = f2b(v0.x); pk[1] = f2b(v0.y); pk[2] = f2b(v0.z); pk[3] = f2b(v0.w);
        pk[4] = f2b(v1.x); pk[5] = f2b(v1.y); pk[6] = f2b(v1.z); pk[7] = f2b(v1.w);
        *(short8*)(WrowL + (((cw + q * 8) * 2) ^ rxw)) = pk;
      }
    }
    __syncthreads();
#pragma unroll
    for (int ks = 0; ks < 64; ks += 32) {
      short8 af[4], wf[2];
#pragma unroll
      for (int mf = 0; mf < 4; ++mf) {
        int rr = wm + mf * 16 + l15;
        af[mf] = *(const short8*)((const char*)Al + rr * 128 +
                                  (((ks + l4 * 8) * 2) ^ ((rr & 7) << 4)));
      }
#pragma unroll
      for (int nf = 0; nf < 2; ++nf) {
        int rr = wn + nf * 16 + l15;
        wf[nf] = *(const short8*)((const char*)Wl + rr * 128 +
                                  (((ks + l4 * 8) * 2) ^ ((rr & 7) << 4)));
      }
#pragma unroll
      for (int mf = 0; mf < 4; ++mf)
#pragma unroll
        for (int nf = 0; nf < 2; ++nf)
          acc[mf][nf] = __builtin_amdgcn_mfma_f32_16x16x32_bf16(
              af[mf], wf[nf], acc[mf][nf], 0, 0, 0);
    }
    __syncthreads();
  }
#pragma unroll
  for (int mf = 0; mf < 4; ++mf) {
#pragma unroll
    for (int nf = 0; nf < 2; ++nf) {
      int col = n0 + wn + nf * 16 + l15;
      float bv = (EPI >= 1 && EPI <= 3) ? bias[col] : 0.f;
      if (EPI == 3) {
        int row0 = m0 + wm + mf * 16 + l4 * 4;
        float4 o;
#pragma unroll
        for (int reg = 0; reg < 4; ++reg) {
          int row = row0 + reg;
          float rv = RESB ? bf2f(((const short*)residv)[(size_t)row * CHN + col])
                          : ((const float*)residv)[(size_t)row * CHN + col];
          ((float*)&o)[reg] = acc[mf][nf][reg] + bv + rv;
        }
        int bb_l = row0 >> 12, row_l = row0 & 4095;
        *(float4*)&outT[((size_t)bb_l * CHN + col) * LEN + row_l] = o;
      } else if (EPI == 4) {
        int row0 = m0 + wm + mf * 16 + l4 * 4;
        int bb_l = row0 >> 12, row_l = row0 & 4095;
        float4 xv = *(const float4*)&((const float*)residv)[((size_t)bb_l * CHN + col) * LEN + row_l];
#pragma unroll
        for (int reg = 0; reg < 4; ++reg) {
          float v = acc[mf][nf][reg] + ((const float*)&xv)[reg];
          if (OBF16) ((short*)Cv)[(size_t)(row0 + reg) * ldc + col] = f2b(v);
          else       ((float*)Cv)[(size_t)(row0 + reg) * ldc + col] = v;
        }
      } else {
#pragma unroll
        for (int reg = 0; reg < 4; ++reg) {
          int row = m0 + wm + mf * 16 + l4 * 4 + reg;
          float v = acc[mf][nf][reg];
          if (EPI >= 1) v += bv;
          if (EPI == 1) v = 0.5f * v * (1.f + erff(v * 0.70710678118f));
          if (OBF16) ((short*)Cv)[(size_t)row * ldc + col] = f2b(v);
          else       ((float*)Cv)[(size_t)row * ldc + col] = v;
        }
      }
    }
  }
}

// ---------------- K5: LDS-tiled causal depthwise conv(4) + bias + silu -> xbcs (bf16)
__global__ __launch_bounds__(256) void k_conv(const short* __restrict__ zxs,
    const float* __restrict__ cw, const float* __restrict__ cb,
    short* __restrict__ xbcs) {
  __shared__ float S[67][132];
  int l0 = blockIdx.x * 64, ct = blockIdx.y, bb = blockIdx.z;
  int tid = threadIdx.x;
  int c = (tid & 31) * 4;
  int chb = ct * 128 + c;
  float wr[4][4];
#pragma unroll
  for (int j = 0; j < 4; ++j) {
    float4 w4 = *(const float4*)&cw[(size_t)(chb + j) * 4];
    wr[j][0] = w4.x; wr[j][1] = w4.y; wr[j][2] = w4.z; wr[j][3] = w4.w;
  }
  float4 bc4 = *(const float4*)&cb[chb];
  for (int idx = tid; idx < 67 * 16; idx += 256) {
    int r = idx >> 4, c8 = (idx & 15) * 8;
    int tok = l0 + r - 3;
    if (tok >= 0) {
      short8 v = *(const short8*)&zxs[((size_t)bb * LEN + tok) * 896 + 384 + ct * 128 + c8];
#pragma unroll
      for (int j = 0; j < 8; ++j) S[r][c8 + j] = bf2f(v[j]);
    } else {
#pragma unroll
      for (int j = 0; j < 8; ++j) S[r][c8 + j] = 0.f;
    }
  }
  __syncthreads();
  int t0l = tid >> 5;
#pragma unroll
  for (int it = 0; it < 8; ++it) {
    int tl = it * 8 + t0l;
    float a0 = bc4.x, a1 = bc4.y, a2 = bc4.z, a3 = bc4.w;
#pragma unroll
    for (int k = 0; k < 4; ++k) {
      float4 v = *(const float4*)&S[tl + k][c];
      a0 += v.x * wr[0][k];
      a1 += v.y * wr[1][k];
      a2 += v.z * wr[2][k];
      a3 += v.w * wr[3][k];
    }
    short4v o;
    o[0] = f2b(a0 / (1.f + __expf(-a0)));
    o[1] = f2b(a1 / (1.f + __expf(-a1)));
    o[2] = f2b(a2 / (1.f + __expf(-a2)));
    o[3] = f2b(a3 / (1.f + __expf(-a3)));
    *(short4v*)&xbcs[((size_t)bb * LEN + l0 + tl) * 512 + chb] = o;
  }
}

// ---------------- K5b: per-(chunk,head) inclusive cumsum of dt*A -> sAg
__global__ __launch_bounds__(256) void k_cumsum(const float* __restrict__ dtb,
    const float* __restrict__ A_log, float* __restrict__ sAg) {
  int cch = blockIdx.x, bb = blockIdx.y;
  int lane = threadIdx.x & 63, wv = threadIdx.x >> 6;
  size_t rowbase = (size_t)bb * LEN + cch * 256;
  for (int h = wv; h < NHEAD; h += 4) {
    float Ah = -expf(A_log[h]);
    float v[4];
#pragma unroll
    for (int i = 0; i < 4; ++i)
      v[i] = dtb[(rowbase + lane * 4 + i) * NHEAD + h] * Ah;
    v[1] += v[0]; v[2] += v[1]; v[3] += v[2];
    float tot = v[3];
    float sc = tot;
    for (int off = 1; off < 64; off <<= 1) {
      float o = __shfl_up(sc, off);
      if (lane >= off) sc += o;
    }
    float excl = sc - tot;
#pragma unroll
    for (int i = 0; i < 4; ++i)
      sAg[(rowbase + lane * 4 + i) * NHEAD + h] = v[i] + excl;
  }
}

// ---------------- K5c: build XT[p][s]=x*dt (global) + FUSED chunk-states MFMA.
__global__ __launch_bounds__(256) void k_xt(const short* __restrict__ xbcs,
    const float* __restrict__ dtb, const float* __restrict__ sAg,
    short* __restrict__ XT, float* __restrict__ states) {
  int cch = blockIdx.x, h = blockIdx.y, bb = blockIdx.z;
  int tid = threadIdx.x;
  int lane = tid & 63, wv = tid >> 6;
  int l15 = lane & 15, l4 = lane >> 4;
  __shared__ float sD[256], sEl[256];
  __shared__ float T[64][68];
  __shared__ short XEl[64 * 64];  // [p][s_loc] swizzled
  __shared__ short BTl[64 * 64];  // [n][s_loc] swizzled
  size_t rowbase = (size_t)bb * LEN + cch * 256;
  sD[tid] = dtb[(rowbase + tid) * NHEAD + h];
  {
    float a = sAg[(rowbase + tid) * NHEAD + h];
    float atot = sAg[(rowbase + 255) * NHEAD + h];
    sEl[tid] = __expf(atot - a);
  }
  size_t base_xh = (((size_t)bb * NHEAD + h) * NCHK + cch) * 16384;
  int r = tid >> 2, cq = (tid & 3) * 16;
  int p = tid >> 2, sq = tid & 3;
  int pswz = (p & 7) << 4;
  f32x4 stacc[4] = {};
  for (int ts = 0; ts < 4; ++ts) {
    __syncthreads();  // T/XEl/BTl free; sD/sEl ready (first iter)
#pragma unroll
    for (int q = 0; q < 2; ++q) {
      short8 v = *(const short8*)&xbcs[(rowbase + ts * 64 + r) * 512 + h * 64 + cq + q * 8];
#pragma unroll
      for (int j = 0; j < 8; ++j) T[r][cq + q * 8 + j] = bf2f(v[j]);
    }
    __syncthreads();
    {
      short8 x0, x1, e0, e1;
#pragma unroll
      for (int j = 0; j < 8; ++j) {
        int sl = sq * 16 + j;
        float f = T[sl][p] * sD[ts * 64 + sl];
        x0[j] = f2b(f);
        e0[j] = f2b(f * sEl[ts * 64 + sl]);
      }
#pragma unroll
      for (int j = 0; j < 8; ++j) {
        int sl = sq * 16 + 8 + j;
        float f = T[sl][p] * sD[ts * 64 + sl];
        x1[j] = f2b(f);
        e1[j] = f2b(f * sEl[ts * 64 + sl]);
      }
      size_t o = base_xh + (size_t)p * 256 + ts * 64 + sq * 16;
      *(short8*)&XT[o] = x0; *(short8*)&XT[o + 8] = x1;
      *(short8*)((char*)XEl + p * 128 + ((sq * 32) ^ pswz)) = e0;
      *(short8*)((char*)XEl + p * 128 + ((sq * 32 + 16) ^ pswz)) = e1;
    }
    __syncthreads();  // T reads done; restage with B
#pragma unroll
    for (int q = 0; q < 2; ++q) {
      short8 bv = *(const short8*)&xbcs[(rowbase + ts * 64 + r) * 512 + 384 + cq + q * 8];
#pragma unroll
      for (int j = 0; j < 8; ++j) T[r][cq + q * 8 + j] = bf2f(bv[j]);
    }
    __syncthreads();
    {
      short8 b0, b1;
#pragma unroll
      for (int j = 0; j < 8; ++j) b0[j] = f2b(T[sq * 16 + j][p]);
#pragma unroll
      for (int j = 0; j < 8; ++j) b1[j] = f2b(T[sq * 16 + 8 + j][p]);
      *(short8*)((char*)BTl + p * 128 + ((sq * 32) ^ pswz)) = b0;
      *(short8*)((char*)BTl + p * 128 + ((sq * 32 + 16) ^ pswz)) = b1;
    }
    __syncthreads();  // XEl/BTl ready
#pragma unroll
    for (int ks = 0; ks < 2; ++ks) {
      int rp = wv * 16 + l15;
      short8 aE = *(const short8*)((const char*)XEl + rp * 128 +
                                   (((ks * 32 + l4 * 8) * 2) ^ ((rp & 7) << 4)));
#pragma unroll
      for (int ni = 0; ni < 4; ++ni) {
        int rn = ni * 16 + l15;
        short8 bB = *(const short8*)((const char*)BTl + rn * 128 +
                                     (((ks * 32 + l4 * 8) * 2) ^ ((rn & 7) << 4)));
        stacc[ni] = __builtin_amdgcn_mfma_f32_16x16x32_bf16(aE, bB, stacc[ni], 0, 0, 0);
      }
    }
  }
  size_t stbase = (((size_t)bb * NCHK + cch) * NHEAD + h) * 4096;
#pragma unroll
  for (int ni = 0; ni < 4; ++ni)
#pragma unroll
    for (int reg = 0; reg < 4; ++reg)
      states[stbase + (size_t)(wv * 16 + l4 * 4 + reg) * 64 + ni * 16 + l15] =
          stacc[ni][reg];
}

// ---------------- K7: inter-chunk scan -> bf16 Sin
__global__ void k_scan(const float* __restrict__ states, const float* __restrict__ sAg,
                       short* __restrict__ SinB) {
  int h = blockIdx.x, bb = blockIdx.y;
  int t = threadIdx.x;
  float S[16];
#pragma unroll
  for (int i = 0; i < 16; ++i) S[i] = 0.f;
  for (int z = 0; z < NCHK; ++z) {
    size_t base = (((size_t)bb * NCHK + z) * NHEAD + h) * 4096 + t * 16;
#pragma unroll
    for (int i = 0; i < 16; ++i) SinB[base + i] = f2b(S[i]);
    float az = __expf(sAg[((size_t)bb * LEN + z * 256 + 255) * NHEAD + h]);
#pragma unroll
    for (int i = 0; i < 16; ++i) S[i] = S[i] * az + states[base + i];
  }
}

// ---------------- K6b: y = Y_diag + Y_off, single bf16 write.
// Balanced chunk-pair + p-split: blockIdx.x = phalf*8 + cq (siblings 8 apart
// -> same XCD). Each block computes only p in [phalf*32, phalf*32+32);
// phase-1 S is recomputed per sibling (cheap at low MfmaUtil).
__global__ __launch_bounds__(256) void k_ssdY(const short* __restrict__ xbcs,
    const short* __restrict__ XT, const short* __restrict__ SinB,
    const float* __restrict__ sAg, short* __restrict__ ybs) {
  int bx = blockIdx.x;
  int cq = bx & 7, phalf = bx >> 3;
  int poff = phalf * 32;
  int h = blockIdx.y, bb = blockIdx.z;
  int tid = threadIdx.x;
  int lane = tid & 63, wv = tid >> 6;
  int l15 = lane & 15, l4 = lane >> 4;
  __shared__ float sA[2][256];
  __shared__ float sEt[2][256];
  __shared__ short St[4][64 * 64];   // per-wave private 8KB
  for (int i = tid; i < 512; i += 256) {
    int cc = i >> 8, off = i & 255;
    float av = sAg[((size_t)bb * LEN + (cq * 2 + cc) * 256 + off) * NHEAD + h];
    sA[cc][off] = av;
    sEt[cc][off] = __expf(av);
  }
  __syncthreads();  // only barrier
  short* Sw = St[wv];
#pragma unroll
  for (int j = 0; j < 2; ++j) {
    int cc = (j == 0) ? (wv & 1) : (1 - (wv & 1));
    int tp = (j == 0) ? (3 - (wv >> 1)) : (wv >> 1);
    int cch = cq * 2 + cc;
    size_t rowbase = (size_t)bb * LEN + cch * 256;
    size_t base_xh = (((size_t)bb * NHEAD + h) * NCHK + cch) * 16384;
    size_t base_s = (((size_t)bb * NCHK + cch) * NHEAD + h) * 4096;
    const float* sAc = sA[cc];
    const float* sEc = sEt[cc];
    short8 cf[4][2];
#pragma unroll
    for (int ni = 0; ni < 4; ++ni)
#pragma unroll
      for (int ks = 0; ks < 2; ++ks)
        cf[ni][ks] = *(const short8*)&xbcs[(rowbase + tp * 64 + ni * 16 + l15) * 512 +
                                           448 + ks * 32 + l4 * 8];
    float At[4];
#pragma unroll
    for (int ni = 0; ni < 4; ++ni) At[ni] = sAc[tp * 64 + ni * 16 + l15];

    f32x4 yacc[2][4];  // [mi over p-half][ni over t]
    // Y_off: D[p][t] = sum_n Sin[p][n]*C[t][n], scaled by exp(Acs[t])
#pragma unroll
    for (int mi = 0; mi < 2; ++mi) {
      f32x4 yo[4] = {};
#pragma unroll
      for (int ks = 0; ks < 2; ++ks) {
        short8 aS = *(const short8*)&SinB[base_s +
            (size_t)(poff + mi * 16 + l15) * 64 + ks * 32 + l4 * 8];
#pragma unroll
        for (int ni = 0; ni < 4; ++ni)
          yo[ni] = __builtin_amdgcn_mfma_f32_16x16x32_bf16(aS, cf[ni][ks], yo[ni], 0, 0, 0);
      }
#pragma unroll
      for (int ni = 0; ni < 4; ++ni) {
        float et = sEc[tp * 64 + ni * 16 + l15];
#pragma unroll
        for (int reg = 0; reg < 4; ++reg) yacc[mi][ni][reg] = et * yo[ni][reg];
      }
    }
    // Y_diag
    for (int st = 0; st <= tp; ++st) {
      bool diag = (st == tp);
#pragma unroll
      for (int mi = 0; mi < 4; ++mi) {
        const short* brow = &xbcs[(rowbase + st * 64 + mi * 16 + l15) * 512 + 384 + l4 * 8];
        short8 af0 = *(const short8*)brow;
        short8 af1 = *(const short8*)(brow + 32);
        f32x4 s0[4];
#pragma unroll
        for (int ni = 0; ni < 4; ++ni) {
          f32x4 t = {};
          t = __builtin_amdgcn_mfma_f32_16x16x32_bf16(af0, cf[ni][0], t, 0, 0, 0);
          t = __builtin_amdgcn_mfma_f32_16x16x32_bf16(af1, cf[ni][1], t, 0, 0, 0);
          s0[ni] = t;
        }
        float As[4];
#pragma unroll
        for (int reg = 0; reg < 4; ++reg) As[reg] = sAc[st * 64 + mi * 16 + l4 * 4 + reg];
        int s_loc0 = mi * 16 + l4 * 4;
#pragma unroll
        for (int ni = 0; ni < 4; ++ni) {
          int t_loc = ni * 16 + l15;
          short4v pk;
#pragma unroll
          for (int reg = 0; reg < 4; ++reg) {
            float v = __expf(At[ni] - As[reg]) * s0[ni][reg];
            if (diag && (s_loc0 + reg) > t_loc) v = 0.f;
            pk[reg] = f2b(v);
          }
          *(short4v*)((char*)Sw + t_loc * 128 +
                      (((s_loc0 * 2)) ^ ((t_loc & 7) << 4))) = pk;
        }
      }
#pragma unroll
      for (int ks = 0; ks < 2; ++ks) {
        short8 bS[4], aX[2];
#pragma unroll
        for (int ni = 0; ni < 4; ++ni) {
          int rt = ni * 16 + l15;
          bS[ni] = *(const short8*)((const char*)Sw + rt * 128 +
                                    (((ks * 32 + l4 * 8) * 2) ^ ((rt & 7) << 4)));
        }
#pragma unroll
        for (int mi = 0; mi < 2; ++mi)
          aX[mi] = *(const short8*)&XT[base_xh +
              (size_t)(poff + mi * 16 + l15) * 256 + st * 64 + ks * 32 + l4 * 8];
#pragma unroll
        for (int mi = 0; mi < 2; ++mi)
#pragma unroll
          for (int ni = 0; ni < 4; ++ni)
            yacc[mi][ni] = __builtin_amdgcn_mfma_f32_16x16x32_bf16(
                aX[mi], bS[ni], yacc[mi][ni], 0, 0, 0);
      }
    }
    // single bf16 y write (p-half only)
#pragma unroll
    for (int ni = 0; ni < 4; ++ni) {
      int tg = tp * 64 + ni * 16 + l15;
#pragma unroll
      for (int mi = 0; mi < 2; ++mi) {
        short4v o;
#pragma unroll
        for (int reg = 0; reg < 4; ++reg) o[reg] = f2b(yacc[mi][ni][reg]);
        *(short4v*)&ybs[(rowbase + tg) * DI + h * 64 + poff + mi * 16 + l4 * 4] = o;
      }
    }
  }
}

// ---------------- K9: g = (y + D_skip*x)*silu(z); RMSNorm(384)*w -> gn (bf16)
__global__ __launch_bounds__(128) void k_gate(const short* __restrict__ ybs,
    const short* __restrict__ zxs, const short* __restrict__ xbcs,
    const float* __restrict__ Dsk, const float* __restrict__ nw,
    short* __restrict__ gn) {
  int row = blockIdx.x;
  int tid = threadIdx.x;
  float g[3]; float sq = 0.f;
#pragma unroll
  for (int i = 0; i < 3; ++i) {
    int d = tid + i * 128;
    int h = d >> 6;
    float z = bf2f(zxs[(size_t)row * 896 + d]);
    float yy = bf2f(ybs[(size_t)row * DI + d]) +
               Dsk[h] * bf2f(xbcs[(size_t)row * 512 + d]);
    float gg = yy * (z / (1.f + expf(-z)));
    g[i] = gg; sq += gg * gg;
  }
  for (int off = 32; off > 0; off >>= 1) sq += __shfl_down(sq, off);
  __shared__ float wsum[2];
  if ((tid & 63) == 0) wsum[tid >> 6] = sq;
  __syncthreads();
  float rs = rsqrtf((wsum[0] + wsum[1]) / 384.f + 1e-5f);
#pragma unroll
  for (int i = 0; i < 3; ++i) {
    int d = tid + i * 128;
    gn[(size_t)row * DI + d] = f2b(g[i] * rs * nw[d]);
  }
}

// ---------------- K12: plain LayerNorm over 192 (bf16 resid) -> bf16 h2
__global__ __launch_bounds__(64) void k_ln2(const short* __restrict__ r,
    const float* __restrict__ w, const float* __restrict__ b, short* __restrict__ h2) {
  int row = blockIdx.x;
  int tid = threadIdx.x;
  float v[3]; float sum = 0.f;
#pragma unroll
  for (int i = 0; i < 3; ++i) { v[i] = bf2f(r[(size_t)row * CHN + tid + i * 64]); sum += v[i]; }
  for (int off = 32; off > 0; off >>= 1) sum += __shfl_down(sum, off);
  sum = __shfl(sum, 0);
  float mu = sum / 192.f;
  float sq = 0.f;
#pragma unroll
  for (int i = 0; i < 3; ++i) { float d = v[i] - mu; sq += d * d; }
  for (int off = 32; off > 0; off >>= 1) sq += __shfl_down(sq, off);
  sq = __shfl(sq, 0);
  float rs = rsqrtf(sq / 192.f + 1e-5f);
#pragma unroll
  for (int i = 0; i < 3; ++i) {
    int c = tid + i * 64;
    h2[(size_t)row * CHN + c] = f2b((v[i] - mu) * rs * w[c] + b[c]);
  }
}

extern "C" void kernel_launch(void* const* d_in, const int* in_sizes, int n_in,
                              void* d_out, int out_size, void* d_ws, size_t ws_size,
                              hipStream_t stream) {
  const float* x     = (const float*)d_in[0];
  const float* n1w   = (const float*)d_in[1];
  const float* n1b   = (const float*)d_in[2];
  const float* win   = (const float*)d_in[3];
  const float* cw    = (const float*)d_in[4];
  const float* cb    = (const float*)d_in[5];
  const float* dtbw  = (const float*)d_in[6];
  const float* alog  = (const float*)d_in[7];
  const float* dskip = (const float*)d_in[8];
  const float* snw   = (const float*)d_in[9];
  const float* wout  = (const float*)d_in[10];
  const float* n2w   = (const float*)d_in[11];
  const float* n2b   = (const float*)d_in[12];
  const float* w1    = (const float*)d_in[13];
  const float* b1    = (const float*)d_in[14];
  const float* w2    = (const float*)d_in[15];
  const float* b2    = (const float*)d_in[16];
  float* out = (float*)d_out;

  int g = 8;
  size_t G192, S_ZXH, S_DT, S_XBCH, S_ST;
  for (;;) {
    G192   = (size_t)g * LEN * CHN;          // floats
    S_ZXH  = (size_t)g * LEN * 448;          // zxs bf16 in float units
    S_DT   = (size_t)g * LEN * NHEAD;
    S_XBCH = (size_t)g * LEN * 256;          // xbcs bf16 in float units
    S_ST   = (size_t)g * NCHK * NHEAD * 4096;
    size_t TOTAL = 2 * G192 + S_ZXH + 2 * S_DT + S_XBCH + G192 / 2 +
                   2 * G192 + S_ST + S_ST / 2 + 64;
    if (TOTAL * 4 <= ws_size) break;
    if (g == 1) return;
    g >>= 1;
  }

  float* ws   = (float*)d_ws;
  short* h1b  = (short*)ws;                  // first G192/2 floats (bf16)
  short* ybs  = (short*)ws;                  // alias (h1b dead after k_udt)
  short* zxs  = (short*)(ws + 2 * G192);
  float* dtb  = ws + 2 * G192 + S_ZXH;
  float* sag  = dtb + S_DT;
  float* xbp  = sag + S_DT;                  // xbcs region
  short* xbcs = (short*)xbp;
  short* f1s  = (short*)xbp;                 // alias (xbcs dead after gate)
  float* up   = xbp + S_XBCH;                // Ubf / h2s region
  short* Ubf  = (short*)up;
  short* h2s  = (short*)up;                  // alias (Ubf dead after in_proj)
  float* xtp  = up + G192 / 2;               // XT / gns region
  short* XT   = (short*)xtp;
  short* gns  = (short*)xtp;                 // alias (XT dead after ssdY)
  float* xep  = xtp + G192;                  // resid region (bf16)
  short* resb = (short*)xep;
  float* st   = xep + G192;                  // states f32
  short* SinB = (short*)(st + S_ST);

  const int M = g * LEN;

  for (int b0 = 0; b0 < BATCH; b0 += g) {
    const float* xg  = x   + (size_t)b0 * CHN * LEN;
    float*       og  = out + (size_t)b0 * CHN * LEN;

    k_ln1<<<dim3(LEN / 32, g), 256, 0, stream>>>(xg, n1w, n1b, h1b);
    k_udt<<<dim3(LEN / 64, g), 256, 0, stream>>>(h1b, win, dtbw, Ubf, dtb);
    gemm_mfma<0, 1, 1, 0><<<dim3(896 / 64, M / 128), 256, 0, stream>>>(
        Ubf, win, nullptr, zxs, M, 896, CHN, 896, nullptr, nullptr);
    k_conv<<<dim3(LEN / 64, 4, g), 256, 0, stream>>>(zxs, cw, cb, xbcs);
    k_cumsum<<<dim3(NCHK, g), 256, 0, stream>>>(dtb, alog, sag);
    k_xt<<<dim3(NCHK, NHEAD, g), 256, 0, stream>>>(xbcs, dtb, sag, XT, st);
    k_scan<<<dim3(NHEAD, g), 256, 0, stream>>>(st, sag, SinB);
    // p-split balanced ssdY: grid x = phalf*8 + cq
    k_ssdY<<<dim3(16, NHEAD, g), 256, 0, stream>>>(xbcs, XT, SinB, sag, ybs);
    k_gate<<<dim3(M), 128, 0, stream>>>(ybs, zxs, xbcs, dskip, snw, gns);
    gemm_mfma<4, 1, 1, 0><<<dim3(CHN / 64, M / 128), 256, 0, stream>>>(
        gns, wout, nullptr, resb, M, CHN, DI, CHN, xg, nullptr);
    k_ln2<<<dim3(M), 64, 0, stream>>>(resb, n2w, n2b, h2s);
    gemm_mfma<1, 1, 1, 0><<<dim3(DI / 64, M / 128), 256, 0, stream>>>(
        h2s, w1, b1, f1s, M, DI, CHN, DI, nullptr, nullptr);
    gemm_mfma<3, 1, 0, 1><<<dim3(CHN / 64, M / 128), 256, 0, stream>>>(
        f1s, w2, b2, nullptr, M, CHN, DI, CHN, resb, og);
  }
}

// Round 23
// 239.708 us; speedup vs baseline: 1.0566x; 1.0566x over previous
//
#include <hip/hip_runtime.h>
#include <hip/hip_bf16.h>

#define BATCH 8
#define CHN   192      // d_model
#define LEN   4096     // H*W tokens
#define DI    384      // d_inner
#define NHEAD 6
#define DST   64       // d_state
#define NCHK  16       // chunks (LEN/256)

typedef __attribute__((ext_vector_type(8))) short short8;
typedef __attribute__((ext_vector_type(4))) short short4v;
typedef __attribute__((ext_vector_type(4))) float f32x4;

// wave-local LDS ordering fence: drain all outstanding LDS ops, and stop the
// scheduler from hoisting later memory ops above it (guide rule #18).
#define LDS_FENCE() do { \
  asm volatile("s_waitcnt lgkmcnt(0)" ::: "memory"); \
  __builtin_amdgcn_sched_barrier(0); \
} while (0)

__device__ __forceinline__ short f2b(float f) {
  unsigned u = __builtin_bit_cast(unsigned, f);
  unsigned r = (u + 0x7FFFu + ((u >> 16) & 1u)) >> 16;  // round-to-nearest-even
  return (short)r;
}
__device__ __forceinline__ float bf2f(short s) {
  unsigned u = ((unsigned)(unsigned short)s) << 16;
  return __builtin_bit_cast(float, u);
}

// ---------------- K1: transposing LayerNorm1: x (g,192,L) f32 -> h1b (g,L,192) bf16
__global__ __launch_bounds__(256) void k_ln1(const float* __restrict__ x,
    const float* __restrict__ w, const float* __restrict__ b, short* __restrict__ h1b) {
  __shared__ float s[192][33];
  __shared__ float red[2][32][8];
  __shared__ float mu_s[32], rs_s[32];
  int bb = blockIdx.y;
  int t0 = blockIdx.x * 32;
  int tid = threadIdx.x;
  for (int i = 0; i < 24; ++i) {
    int idx = tid + i * 256;            // 192*32 = 6144
    int c = idx >> 5, tt = idx & 31;
    s[c][tt] = x[((size_t)bb * CHN + c) * LEN + t0 + tt];
  }
  __syncthreads();
  int tok = tid & 31, part = tid >> 5;
  float sum = 0.f, sq = 0.f;
  for (int c = part * 24; c < part * 24 + 24; ++c) { float v = s[c][tok]; sum += v; sq += v * v; }
  red[0][tok][part] = sum; red[1][tok][part] = sq;
  __syncthreads();
  if (tid < 32) {
    float su = 0.f, qq = 0.f;
    for (int p = 0; p < 8; ++p) { su += red[0][tid][p]; qq += red[1][tid][p]; }
    float mu = su / 192.f;
    float var = qq / 192.f - mu * mu;
    mu_s[tid] = mu; rs_s[tid] = rsqrtf(var + 1e-5f);
  }
  __syncthreads();
  for (int i = 0; i < 24; ++i) {
    int idx = tid + i * 256;
    int c = idx % 192, tt = idx / 192;
    float v = (s[c][tt] - mu_s[tt]) * rs_s[tt] * w[c] + b[c];
    h1b[((size_t)bb * LEN + t0 + tt) * CHN + c] = f2b(v);
  }
}

// ---------------- K2: fused u-view consumer (bf16 h1): Ubf ([l][c]) + dt (f32 acc).
__global__ __launch_bounds__(256) void k_udt(const short* __restrict__ h1b,
    const float* __restrict__ win, const float* __restrict__ dt_bias,
    short* __restrict__ Ub, float* __restrict__ dtb) {
  __shared__ short Utb[192][72];
  __shared__ float Wd[6][192];
  int l0 = blockIdx.x * 64, bb = blockIdx.y;
  int tid = threadIdx.x;
  for (int i = tid; i < 6 * 192; i += 256)
    Wd[i / 192][i % 192] = win[(size_t)(896 + i / 192) * 192 + (i % 192)];
  const short* src = h1b + (size_t)bb * (CHN * LEN);
  for (int i = tid; i < 192 * 8; i += 256) {
    int c = i >> 3, q = i & 7;
    short8 v = *(const short8*)&src[(size_t)c * LEN + l0 + q * 8];
    *(short8*)&Utb[c][q * 8] = v;
  }
  __syncthreads();
  {
    int l = tid >> 2, part = tid & 3;
    short* dst = Ub + ((size_t)bb * LEN + l0 + l) * CHN + part * 48;
#pragma unroll
    for (int q = 0; q < 6; ++q) {
      short8 pk;
#pragma unroll
      for (int j = 0; j < 8; ++j) pk[j] = Utb[part * 48 + q * 8 + j][l];
      *(short8*)&dst[q * 8] = pk;
    }
  }
  int tok = tid & 63, grp = tid >> 6;
  for (int hh = grp; hh < 6; hh += 4) {
    float acc = dt_bias[hh];
    for (int c = 0; c < 192; ++c) acc += bf2f(Utb[c][tok]) * Wd[hh][c];
    dtb[((size_t)bb * LEN + l0 + tok) * NHEAD + hh] =
        (acc > 20.f) ? acc : log1pf(expf(acc));
  }
}

// ---------------- MFMA GEMM: C = A @ W^T, f32 weights. A f32 or bf16 (ABF16).
// EPI 0: C=v ; 1: C=gelu(v+bias) ; 2: C=v+bias ;
// EPI 3: v+bias+resid(row-major; bf16 if RESB) -> TRANSPOSED f32 outT ;
// EPI 4: v + xT(transposed f32 read) -> row-major C (bf16 if OBF16)
template <int EPI, int ABF16, int OBF16, int RESB>
__global__ __launch_bounds__(256) void gemm_mfma(const void* __restrict__ Av,
    const float* __restrict__ W, const float* __restrict__ bias,
    void* __restrict__ Cv, int M, int N, int K, int ldc,
    const void* __restrict__ residv, float* __restrict__ outT) {
  __shared__ short Al[128 * 64];  // row stride 128 B
  __shared__ short Wl[64 * 64];
  int m0 = blockIdx.y * 128, n0 = blockIdx.x * 64;
  int tid = threadIdx.x;
  int lane = tid & 63, wv = tid >> 6;
  int wm = (wv >> 1) * 64, wn = (wv & 1) * 32;
  int l15 = lane & 15, l4 = lane >> 4;
  f32x4 acc[4][2] = {};

  int ra = tid >> 1, ca = (tid & 1) * 32;
  int rw = tid >> 2, cw = (tid & 3) * 16;
  char* ArowL = (char*)Al + ra * 128;
  char* WrowL = (char*)Wl + rw * 128;
  int rxa = (ra & 7) << 4, rxw = (rw & 7) << 4;

  for (int k0 = 0; k0 < K; k0 += 64) {
    if (ABF16) {
      const short* Ag = (const short*)Av + (size_t)(m0 + ra) * K + k0 + ca;
#pragma unroll
      for (int q = 0; q < 4; ++q) {
        short8 pk = *(const short8*)(Ag + q * 8);
        *(short8*)(ArowL + (((ca + q * 8) * 2) ^ rxa)) = pk;
      }
    } else {
      const float* Ag = (const float*)Av + (size_t)(m0 + ra) * K + k0 + ca;
#pragma unroll
      for (int q = 0; q < 4; ++q) {
        float4 v0 = *(const float4*)(Ag + q * 8);
        float4 v1 = *(const float4*)(Ag + q * 8 + 4);
        short8 pk;
        pk[0] = f2b(v0.x); pk[1] = f2b(v0.y); pk[2] = f2b(v0.z); pk[3] = f2b(v0.w);
        pk[4] = f2b(v1.x); pk[5] = f2b(v1.y); pk[6] = f2b(v1.z); pk[7] = f2b(v1.w);
        *(short8*)(ArowL + (((ca + q * 8) * 2) ^ rxa)) = pk;
      }
    }
    {
      const float* Wg = W + (size_t)(n0 + rw) * K + k0 + cw;
#pragma unroll
      for (int q = 0; q < 2; ++q) {
        float4 v0 = *(const float4*)(Wg + q * 8);
        float4 v1 = *(const float4*)(Wg + q * 8 + 4);
        short8 pk;
        pk[0] = f2b(v0.x); pk[1] = f2b(v0.y); pk[2] = f2b(v0.z); pk[3] = f2b(v0.w);
        pk[4] = f2b(v1.x); pk[5] = f2b(v1.y); pk[6] = f2b(v1.z); pk[7] = f2b(v1.w);
        *(short8*)(WrowL + (((cw + q * 8) * 2) ^ rxw)) = pk;
      }
    }
    __syncthreads();
#pragma unroll
    for (int ks = 0; ks < 64; ks += 32) {
      short8 af[4], wf[2];
#pragma unroll
      for (int mf = 0; mf < 4; ++mf) {
        int rr = wm + mf * 16 + l15;
        af[mf] = *(const short8*)((const char*)Al + rr * 128 +
                                  (((ks + l4 * 8) * 2) ^ ((rr & 7) << 4)));
      }
#pragma unroll
      for (int nf = 0; nf < 2; ++nf) {
        int rr = wn + nf * 16 + l15;
        wf[nf] = *(const short8*)((const char*)Wl + rr * 128 +
                                  (((ks + l4 * 8) * 2) ^ ((rr & 7) << 4)));
      }
#pragma unroll
      for (int mf = 0; mf < 4; ++mf)
#pragma unroll
        for (int nf = 0; nf < 2; ++nf)
          acc[mf][nf] = __builtin_amdgcn_mfma_f32_16x16x32_bf16(
              af[mf], wf[nf], acc[mf][nf], 0, 0, 0);
    }
    __syncthreads();
  }
#pragma unroll
  for (int mf = 0; mf < 4; ++mf) {
#pragma unroll
    for (int nf = 0; nf < 2; ++nf) {
      int col = n0 + wn + nf * 16 + l15;
      float bv = (EPI >= 1 && EPI <= 3) ? bias[col] : 0.f;
      if (EPI == 3) {
        int row0 = m0 + wm + mf * 16 + l4 * 4;
        float4 o;
#pragma unroll
        for (int reg = 0; reg < 4; ++reg) {
          int row = row0 + reg;
          float rv = RESB ? bf2f(((const short*)residv)[(size_t)row * CHN + col])
                          : ((const float*)residv)[(size_t)row * CHN + col];
          ((float*)&o)[reg] = acc[mf][nf][reg] + bv + rv;
        }
        int bb_l = row0 >> 12, row_l = row0 & 4095;
        *(float4*)&outT[((size_t)bb_l * CHN + col) * LEN + row_l] = o;
      } else if (EPI == 4) {
        int row0 = m0 + wm + mf * 16 + l4 * 4;
        int bb_l = row0 >> 12, row_l = row0 & 4095;
        float4 xv = *(const float4*)&((const float*)residv)[((size_t)bb_l * CHN + col) * LEN + row_l];
#pragma unroll
        for (int reg = 0; reg < 4; ++reg) {
          float v = acc[mf][nf][reg] + ((const float*)&xv)[reg];
          if (OBF16) ((short*)Cv)[(size_t)(row0 + reg) * ldc + col] = f2b(v);
          else       ((float*)Cv)[(size_t)(row0 + reg) * ldc + col] = v;
        }
      } else {
#pragma unroll
        for (int reg = 0; reg < 4; ++reg) {
          int row = m0 + wm + mf * 16 + l4 * 4 + reg;
          float v = acc[mf][nf][reg];
          if (EPI >= 1) v += bv;
          if (EPI == 1) v = 0.5f * v * (1.f + erff(v * 0.70710678118f));
          if (OBF16) ((short*)Cv)[(size_t)row * ldc + col] = f2b(v);
          else       ((float*)Cv)[(size_t)row * ldc + col] = v;
        }
      }
    }
  }
}

// ---------------- K5: LDS-tiled causal depthwise conv(4) + bias + silu -> xbcs (bf16)
__global__ __launch_bounds__(256) void k_conv(const short* __restrict__ zxs,
    const float* __restrict__ cw, const float* __restrict__ cb,
    short* __restrict__ xbcs) {
  __shared__ float S[67][132];
  int l0 = blockIdx.x * 64, ct = blockIdx.y, bb = blockIdx.z;
  int tid = threadIdx.x;
  int c = (tid & 31) * 4;
  int chb = ct * 128 + c;
  float wr[4][4];
#pragma unroll
  for (int j = 0; j < 4; ++j) {
    float4 w4 = *(const float4*)&cw[(size_t)(chb + j) * 4];
    wr[j][0] = w4.x; wr[j][1] = w4.y; wr[j][2] = w4.z; wr[j][3] = w4.w;
  }
  float4 bc4 = *(const float4*)&cb[chb];
  for (int idx = tid; idx < 67 * 16; idx += 256) {
    int r = idx >> 4, c8 = (idx & 15) * 8;
    int tok = l0 + r - 3;
    if (tok >= 0) {
      short8 v = *(const short8*)&zxs[((size_t)bb * LEN + tok) * 896 + 384 + ct * 128 + c8];
#pragma unroll
      for (int j = 0; j < 8; ++j) S[r][c8 + j] = bf2f(v[j]);
    } else {
#pragma unroll
      for (int j = 0; j < 8; ++j) S[r][c8 + j] = 0.f;
    }
  }
  __syncthreads();
  int t0l = tid >> 5;
#pragma unroll
  for (int it = 0; it < 8; ++it) {
    int tl = it * 8 + t0l;
    float a0 = bc4.x, a1 = bc4.y, a2 = bc4.z, a3 = bc4.w;
#pragma unroll
    for (int k = 0; k < 4; ++k) {
      float4 v = *(const float4*)&S[tl + k][c];
      a0 += v.x * wr[0][k];
      a1 += v.y * wr[1][k];
      a2 += v.z * wr[2][k];
      a3 += v.w * wr[3][k];
    }
    short4v o;
    o[0] = f2b(a0 / (1.f + __expf(-a0)));
    o[1] = f2b(a1 / (1.f + __expf(-a1)));
    o[2] = f2b(a2 / (1.f + __expf(-a2)));
    o[3] = f2b(a3 / (1.f + __expf(-a3)));
    *(short4v*)&xbcs[((size_t)bb * LEN + l0 + tl) * 512 + chb] = o;
  }
}

// ---------------- K5b: per-(chunk,head) inclusive cumsum of dt*A -> sAg
__global__ __launch_bounds__(256) void k_cumsum(const float* __restrict__ dtb,
    const float* __restrict__ A_log, float* __restrict__ sAg) {
  int cch = blockIdx.x, bb = blockIdx.y;
  int lane = threadIdx.x & 63, wv = threadIdx.x >> 6;
  size_t rowbase = (size_t)bb * LEN + cch * 256;
  for (int h = wv; h < NHEAD; h += 4) {
    float Ah = -expf(A_log[h]);
    float v[4];
#pragma unroll
    for (int i = 0; i < 4; ++i)
      v[i] = dtb[(rowbase + lane * 4 + i) * NHEAD + h] * Ah;
    v[1] += v[0]; v[2] += v[1]; v[3] += v[2];
    float tot = v[3];
    float sc = tot;
    for (int off = 1; off < 64; off <<= 1) {
      float o = __shfl_up(sc, off);
      if (lane >= off) sc += o;
    }
    float excl = sc - tot;
#pragma unroll
    for (int i = 0; i < 4; ++i)
      sAg[(rowbase + lane * 4 + i) * NHEAD + h] = v[i] + excl;
  }
}

// ---------------- K5c: build XT[p][s]=x*dt (global) + FUSED chunk-states MFMA.
__global__ __launch_bounds__(256) void k_xt(const short* __restrict__ xbcs,
    const float* __restrict__ dtb, const float* __restrict__ sAg,
    short* __restrict__ XT, float* __restrict__ states) {
  int cch = blockIdx.x, h = blockIdx.y, bb = blockIdx.z;
  int tid = threadIdx.x;
  int lane = tid & 63, wv = tid >> 6;
  int l15 = lane & 15, l4 = lane >> 4;
  __shared__ float sD[256], sEl[256];
  __shared__ float T[64][68];
  __shared__ short XEl[64 * 64];  // [p][s_loc] swizzled
  __shared__ short BTl[64 * 64];  // [n][s_loc] swizzled
  size_t rowbase = (size_t)bb * LEN + cch * 256;
  sD[tid] = dtb[(rowbase + tid) * NHEAD + h];
  {
    float a = sAg[(rowbase + tid) * NHEAD + h];
    float atot = sAg[(rowbase + 255) * NHEAD + h];
    sEl[tid] = __expf(atot - a);
  }
  size_t base_xh = (((size_t)bb * NHEAD + h) * NCHK + cch) * 16384;
  int r = tid >> 2, cq = (tid & 3) * 16;
  int p = tid >> 2, sq = tid & 3;
  int pswz = (p & 7) << 4;
  f32x4 stacc[4] = {};
  for (int ts = 0; ts < 4; ++ts) {
    __syncthreads();  // T/XEl/BTl free; sD/sEl ready (first iter)
#pragma unroll
    for (int q = 0; q < 2; ++q) {
      short8 v = *(const short8*)&xbcs[(rowbase + ts * 64 + r) * 512 + h * 64 + cq + q * 8];
#pragma unroll
      for (int j = 0; j < 8; ++j) T[r][cq + q * 8 + j] = bf2f(v[j]);
    }
    __syncthreads();
    {
      short8 x0, x1, e0, e1;
#pragma unroll
      for (int j = 0; j < 8; ++j) {
        int sl = sq * 16 + j;
        float f = T[sl][p] * sD[ts * 64 + sl];
        x0[j] = f2b(f);
        e0[j] = f2b(f * sEl[ts * 64 + sl]);
      }
#pragma unroll
      for (int j = 0; j < 8; ++j) {
        int sl = sq * 16 + 8 + j;
        float f = T[sl][p] * sD[ts * 64 + sl];
        x1[j] = f2b(f);
        e1[j] = f2b(f * sEl[ts * 64 + sl]);
      }
      size_t o = base_xh + (size_t)p * 256 + ts * 64 + sq * 16;
      *(short8*)&XT[o] = x0; *(short8*)&XT[o + 8] = x1;
      *(short8*)((char*)XEl + p * 128 + ((sq * 32) ^ pswz)) = e0;
      *(short8*)((char*)XEl + p * 128 + ((sq * 32 + 16) ^ pswz)) = e1;
    }
    __syncthreads();  // T reads done; restage with B
#pragma unroll
    for (int q = 0; q < 2; ++q) {
      short8 bv = *(const short8*)&xbcs[(rowbase + ts * 64 + r) * 512 + 384 + cq + q * 8];
#pragma unroll
      for (int j = 0; j < 8; ++j) T[r][cq + q * 8 + j] = bf2f(bv[j]);
    }
    __syncthreads();
    {
      short8 b0, b1;
#pragma unroll
      for (int j = 0; j < 8; ++j) b0[j] = f2b(T[sq * 16 + j][p]);
#pragma unroll
      for (int j = 0; j < 8; ++j) b1[j] = f2b(T[sq * 16 + 8 + j][p]);
      *(short8*)((char*)BTl + p * 128 + ((sq * 32) ^ pswz)) = b0;
      *(short8*)((char*)BTl + p * 128 + ((sq * 32 + 16) ^ pswz)) = b1;
    }
    __syncthreads();  // XEl/BTl ready
#pragma unroll
    for (int ks = 0; ks < 2; ++ks) {
      int rp = wv * 16 + l15;
      short8 aE = *(const short8*)((const char*)XEl + rp * 128 +
                                   (((ks * 32 + l4 * 8) * 2) ^ ((rp & 7) << 4)));
#pragma unroll
      for (int ni = 0; ni < 4; ++ni) {
        int rn = ni * 16 + l15;
        short8 bB = *(const short8*)((const char*)BTl + rn * 128 +
                                     (((ks * 32 + l4 * 8) * 2) ^ ((rn & 7) << 4)));
        stacc[ni] = __builtin_amdgcn_mfma_f32_16x16x32_bf16(aE, bB, stacc[ni], 0, 0, 0);
      }
    }
  }
  size_t stbase = (((size_t)bb * NCHK + cch) * NHEAD + h) * 4096;
#pragma unroll
  for (int ni = 0; ni < 4; ++ni)
#pragma unroll
    for (int reg = 0; reg < 4; ++reg)
      states[stbase + (size_t)(wv * 16 + l4 * 4 + reg) * 64 + ni * 16 + l15] =
          stacc[ni][reg];
}

// ---------------- K7: inter-chunk scan -> bf16 Sin
__global__ void k_scan(const float* __restrict__ states, const float* __restrict__ sAg,
                       short* __restrict__ SinB) {
  int h = blockIdx.x, bb = blockIdx.y;
  int t = threadIdx.x;
  float S[16];
#pragma unroll
  for (int i = 0; i < 16; ++i) S[i] = 0.f;
  for (int z = 0; z < NCHK; ++z) {
    size_t base = (((size_t)bb * NCHK + z) * NHEAD + h) * 4096 + t * 16;
#pragma unroll
    for (int i = 0; i < 16; ++i) SinB[base + i] = f2b(S[i]);
    float az = __expf(sAg[((size_t)bb * LEN + z * 256 + 255) * NHEAD + h]);
#pragma unroll
    for (int i = 0; i < 16; ++i) S[i] = S[i] * az + states[base + i];
  }
}

// ---------------- K6b: y = Y_diag + Y_off, single bf16 write.
// Balanced chunk-pair: block=(cq, h, bb); wave wv does TWO (chunk, t-panel)
// assignments totalling 5 st-iterations each -> all waves equal length.
// Wave-local LDS fences order the private St write->read phases explicitly.
__global__ __launch_bounds__(256) void k_ssdY(const short* __restrict__ xbcs,
    const short* __restrict__ XT, const short* __restrict__ SinB,
    const float* __restrict__ sAg, short* __restrict__ ybs) {
  int cq = blockIdx.x;
  int h = blockIdx.y, bb = blockIdx.z;
  int tid = threadIdx.x;
  int lane = tid & 63, wv = tid >> 6;
  int l15 = lane & 15, l4 = lane >> 4;
  __shared__ float sA[2][256];
  __shared__ float sEt[2][256];
  __shared__ short St[4][64 * 64];   // per-wave private 8KB
  for (int i = tid; i < 512; i += 256) {
    int cc = i >> 8, off = i & 255;
    float av = sAg[((size_t)bb * LEN + (cq * 2 + cc) * 256 + off) * NHEAD + h];
    sA[cc][off] = av;
    sEt[cc][off] = __expf(av);
  }
  __syncthreads();  // only block-wide barrier
  short* Sw = St[wv];
#pragma unroll
  for (int j = 0; j < 2; ++j) {
    int cc = (j == 0) ? (wv & 1) : (1 - (wv & 1));
    int tp = (j == 0) ? (3 - (wv >> 1)) : (wv >> 1);
    int cch = cq * 2 + cc;
    size_t rowbase = (size_t)bb * LEN + cch * 256;
    size_t base_xh = (((size_t)bb * NHEAD + h) * NCHK + cch) * 16384;
    size_t base_s = (((size_t)bb * NCHK + cch) * NHEAD + h) * 4096;
    const float* sAc = sA[cc];
    const float* sEc = sEt[cc];
    short8 cf[4][2];
#pragma unroll
    for (int ni = 0; ni < 4; ++ni)
#pragma unroll
      for (int ks = 0; ks < 2; ++ks)
        cf[ni][ks] = *(const short8*)&xbcs[(rowbase + tp * 64 + ni * 16 + l15) * 512 +
                                           448 + ks * 32 + l4 * 8];
    float At[4];
#pragma unroll
    for (int ni = 0; ni < 4; ++ni) At[ni] = sAc[tp * 64 + ni * 16 + l15];

    f32x4 yacc[4][4];  // [mi over p][ni over t]
    // Y_off: D[p][t] = sum_n Sin[p][n]*C[t][n], scaled by exp(Acs[t])
#pragma unroll
    for (int mi = 0; mi < 4; ++mi) {
      f32x4 yo[4] = {};
#pragma unroll
      for (int ks = 0; ks < 2; ++ks) {
        short8 aS = *(const short8*)&SinB[base_s +
            (size_t)(mi * 16 + l15) * 64 + ks * 32 + l4 * 8];
#pragma unroll
        for (int ni = 0; ni < 4; ++ni)
          yo[ni] = __builtin_amdgcn_mfma_f32_16x16x32_bf16(aS, cf[ni][ks], yo[ni], 0, 0, 0);
      }
#pragma unroll
      for (int ni = 0; ni < 4; ++ni) {
        float et = sEc[tp * 64 + ni * 16 + l15];
#pragma unroll
        for (int reg = 0; reg < 4; ++reg) yacc[mi][ni][reg] = et * yo[ni][reg];
      }
    }
    // Y_diag
    for (int st = 0; st <= tp; ++st) {
      bool diag = (st == tp);
      LDS_FENCE();  // prior phase-2 reads of Sw complete before rewriting it
#pragma unroll
      for (int mi = 0; mi < 4; ++mi) {
        const short* brow = &xbcs[(rowbase + st * 64 + mi * 16 + l15) * 512 + 384 + l4 * 8];
        short8 af0 = *(const short8*)brow;
        short8 af1 = *(const short8*)(brow + 32);
        f32x4 s0[4];
#pragma unroll
        for (int ni = 0; ni < 4; ++ni) {
          f32x4 t = {};
          t = __builtin_amdgcn_mfma_f32_16x16x32_bf16(af0, cf[ni][0], t, 0, 0, 0);
          t = __builtin_amdgcn_mfma_f32_16x16x32_bf16(af1, cf[ni][1], t, 0, 0, 0);
          s0[ni] = t;
        }
        float As[4];
#pragma unroll
        for (int reg = 0; reg < 4; ++reg) As[reg] = sAc[st * 64 + mi * 16 + l4 * 4 + reg];
        int s_loc0 = mi * 16 + l4 * 4;
#pragma unroll
        for (int ni = 0; ni < 4; ++ni) {
          int t_loc = ni * 16 + l15;
          short4v pk;
#pragma unroll
          for (int reg = 0; reg < 4; ++reg) {
            float v = __expf(At[ni] - As[reg]) * s0[ni][reg];
            if (diag && (s_loc0 + reg) > t_loc) v = 0.f;
            pk[reg] = f2b(v);
          }
          *(short4v*)((char*)Sw + t_loc * 128 +
                      (((s_loc0 * 2)) ^ ((t_loc & 7) << 4))) = pk;
        }
      }
      LDS_FENCE();  // phase-1 St writes complete before phase-2 reads
#pragma unroll
      for (int ks = 0; ks < 2; ++ks) {
        short8 bS[4], aX[4];
#pragma unroll
        for (int ni = 0; ni < 4; ++ni) {
          int rt = ni * 16 + l15;
          bS[ni] = *(const short8*)((const char*)Sw + rt * 128 +
                                    (((ks * 32 + l4 * 8) * 2) ^ ((rt & 7) << 4)));
        }
#pragma unroll
        for (int mi = 0; mi < 4; ++mi)
          aX[mi] = *(const short8*)&XT[base_xh +
              (size_t)(mi * 16 + l15) * 256 + st * 64 + ks * 32 + l4 * 8];
#pragma unroll
        for (int mi = 0; mi < 4; ++mi)
#pragma unroll
          for (int ni = 0; ni < 4; ++ni)
            yacc[mi][ni] = __builtin_amdgcn_mfma_f32_16x16x32_bf16(
                aX[mi], bS[ni], yacc[mi][ni], 0, 0, 0);
      }
    }
    // single bf16 y write
#pragma unroll
    for (int ni = 0; ni < 4; ++ni) {
      int tg = tp * 64 + ni * 16 + l15;
#pragma unroll
      for (int mi = 0; mi < 4; ++mi) {
        short4v o;
#pragma unroll
        for (int reg = 0; reg < 4; ++reg) o[reg] = f2b(yacc[mi][ni][reg]);
        *(short4v*)&ybs[(rowbase + tg) * DI + h * 64 + mi * 16 + l4 * 4] = o;
      }
    }
  }
}

// ---------------- K9: g = (y + D_skip*x)*silu(z); RMSNorm(384)*w -> gn (bf16)
__global__ __launch_bounds__(128) void k_gate(const short* __restrict__ ybs,
    const short* __restrict__ zxs, const short* __restrict__ xbcs,
    const float* __restrict__ Dsk, const float* __restrict__ nw,
    short* __restrict__ gn) {
  int row = blockIdx.x;
  int tid = threadIdx.x;
  float g[3]; float sq = 0.f;
#pragma unroll
  for (int i = 0; i < 3; ++i) {
    int d = tid + i * 128;
    int h = d >> 6;
    float z = bf2f(zxs[(size_t)row * 896 + d]);
    float yy = bf2f(ybs[(size_t)row * DI + d]) +
               Dsk[h] * bf2f(xbcs[(size_t)row * 512 + d]);
    float gg = yy * (z / (1.f + expf(-z)));
    g[i] = gg; sq += gg * gg;
  }
  for (int off = 32; off > 0; off >>= 1) sq += __shfl_down(sq, off);
  __shared__ float wsum[2];
  if ((tid & 63) == 0) wsum[tid >> 6] = sq;
  __syncthreads();
  float rs = rsqrtf((wsum[0] + wsum[1]) / 384.f + 1e-5f);
#pragma unroll
  for (int i = 0; i < 3; ++i) {
    int d = tid + i * 128;
    gn[(size_t)row * DI + d] = f2b(g[i] * rs * nw[d]);
  }
}

// ---------------- K12: plain LayerNorm over 192 (bf16 resid) -> bf16 h2
__global__ __launch_bounds__(64) void k_ln2(const short* __restrict__ r,
    const float* __restrict__ w, const float* __restrict__ b, short* __restrict__ h2) {
  int row = blockIdx.x;
  int tid = threadIdx.x;
  float v[3]; float sum = 0.f;
#pragma unroll
  for (int i = 0; i < 3; ++i) { v[i] = bf2f(r[(size_t)row * CHN + tid + i * 64]); sum += v[i]; }
  for (int off = 32; off > 0; off >>= 1) sum += __shfl_down(sum, off);
  sum = __shfl(sum, 0);
  float mu = sum / 192.f;
  float sq = 0.f;
#pragma unroll
  for (int i = 0; i < 3; ++i) { float d = v[i] - mu; sq += d * d; }
  for (int off = 32; off > 0; off >>= 1) sq += __shfl_down(sq, off);
  sq = __shfl(sq, 0);
  float rs = rsqrtf(sq / 192.f + 1e-5f);
#pragma unroll
  for (int i = 0; i < 3; ++i) {
    int c = tid + i * 64;
    h2[(size_t)row * CHN + c] = f2b((v[i] - mu) * rs * w[c] + b[c]);
  }
}

extern "C" void kernel_launch(void* const* d_in, const int* in_sizes, int n_in,
                              void* d_out, int out_size, void* d_ws, size_t ws_size,
                              hipStream_t stream) {
  const float* x     = (const float*)d_in[0];
  const float* n1w   = (const float*)d_in[1];
  const float* n1b   = (const float*)d_in[2];
  const float* win   = (const float*)d_in[3];
  const float* cw    = (const float*)d_in[4];
  const float* cb    = (const float*)d_in[5];
  const float* dtbw  = (const float*)d_in[6];
  const float* alog  = (const float*)d_in[7];
  const float* dskip = (const float*)d_in[8];
  const float* snw   = (const float*)d_in[9];
  const float* wout  = (const float*)d_in[10];
  const float* n2w   = (const float*)d_in[11];
  const float* n2b   = (const float*)d_in[12];
  const float* w1    = (const float*)d_in[13];
  const float* b1    = (const float*)d_in[14];
  const float* w2    = (const float*)d_in[15];
  const float* b2    = (const float*)d_in[16];
  float* out = (float*)d_out;

  int g = 8;
  size_t G192, S_ZXH, S_DT, S_XBCH, S_ST;
  for (;;) {
    G192   = (size_t)g * LEN * CHN;          // floats
    S_ZXH  = (size_t)g * LEN * 448;          // zxs bf16 in float units
    S_DT   = (size_t)g * LEN * NHEAD;
    S_XBCH = (size_t)g * LEN * 256;          // xbcs bf16 in float units
    S_ST   = (size_t)g * NCHK * NHEAD * 4096;
    size_t TOTAL = 2 * G192 + S_ZXH + 2 * S_DT + S_XBCH + G192 / 2 +
                   2 * G192 + S_ST + S_ST / 2 + 64;
    if (TOTAL * 4 <= ws_size) break;
    if (g == 1) return;
    g >>= 1;
  }

  float* ws   = (float*)d_ws;
  short* h1b  = (short*)ws;                  // first G192/2 floats (bf16)
  short* ybs  = (short*)ws;                  // alias (h1b dead after k_udt)
  short* zxs  = (short*)(ws + 2 * G192);
  float* dtb  = ws + 2 * G192 + S_ZXH;
  float* sag  = dtb + S_DT;
  float* xbp  = sag + S_DT;                  // xbcs region
  short* xbcs = (short*)xbp;
  short* f1s  = (short*)xbp;                 // alias (xbcs dead after gate)
  float* up   = xbp + S_XBCH;                // Ubf / h2s region
  short* Ubf  = (short*)up;
  short* h2s  = (short*)up;                  // alias (Ubf dead after in_proj)
  float* xtp  = up + G192 / 2;               // XT / gns region
  short* XT   = (short*)xtp;
  short* gns  = (short*)xtp;                 // alias (XT dead after ssdY)
  float* xep  = xtp + G192;                  // resid region (bf16)
  short* resb = (short*)xep;
  float* st   = xep + G192;                  // states f32
  short* SinB = (short*)(st + S_ST);

  const int M = g * LEN;

  for (int b0 = 0; b0 < BATCH; b0 += g) {
    const float* xg  = x   + (size_t)b0 * CHN * LEN;
    float*       og  = out + (size_t)b0 * CHN * LEN;

    k_ln1<<<dim3(LEN / 32, g), 256, 0, stream>>>(xg, n1w, n1b, h1b);
    k_udt<<<dim3(LEN / 64, g), 256, 0, stream>>>(h1b, win, dtbw, Ubf, dtb);
    gemm_mfma<0, 1, 1, 0><<<dim3(896 / 64, M / 128), 256, 0, stream>>>(
        Ubf, win, nullptr, zxs, M, 896, CHN, 896, nullptr, nullptr);
    k_conv<<<dim3(LEN / 64, 4, g), 256, 0, stream>>>(zxs, cw, cb, xbcs);
    k_cumsum<<<dim3(NCHK, g), 256, 0, stream>>>(dtb, alog, sag);
    k_xt<<<dim3(NCHK, NHEAD, g), 256, 0, stream>>>(xbcs, dtb, sag, XT, st);
    k_scan<<<dim3(NHEAD, g), 256, 0, stream>>>(st, sag, SinB);
    k_ssdY<<<dim3(NCHK / 2, NHEAD, g), 256, 0, stream>>>(xbcs, XT, SinB, sag, ybs);
    k_gate<<<dim3(M), 128, 0, stream>>>(ybs, zxs, xbcs, dskip, snw, gns);
    gemm_mfma<4, 1, 1, 0><<<dim3(CHN / 64, M / 128), 256, 0, stream>>>(
        gns, wout, nullptr, resb, M, CHN, DI, CHN, xg, nullptr);
    k_ln2<<<dim3(M), 64, 0, stream>>>(resb, n2w, n2b, h2s);
    gemm_mfma<1, 1, 1, 0><<<dim3(DI / 64, M / 128), 256, 0, stream>>>(
        h2s, w1, b1, f1s, M, DI, CHN, DI, nullptr, nullptr);
    gemm_mfma<3, 1, 0, 1><<<dim3(CHN / 64, M / 128), 256, 0, stream>>>(
        f1s, w2, b2, nullptr, M, CHN, DI, CHN, resb, og);
  }
}